// Round 3
// baseline (5613.382 us; speedup 1.0000x reference)
//
#include <hip/hip_runtime.h>
#include <math.h>

// ======================= compile-time real Clebsch-Gordan tables =======================

constexpr double FTAB[14]={1.0,1.0,2.0,6.0,24.0,120.0,720.0,5040.0,40320.0,362880.0,
                           3628800.0,39916800.0,479001600.0,6227020800.0};

constexpr double csqrt_(double x){
  if(x<=0.0) return 0.0;
  double g = x<1.0 ? 1.0 : x;
  for(int i=0;i<60;i++){
    double ng=0.5*(g+x/g);
    if(ng==g) break;
    g=ng;
  }
  return g;
}

constexpr double cgc_(int l1,int m1,int l2,int m2,int l3,int m3){
  if(m1+m2!=m3) return 0.0;
  int ad = l1>l2 ? l1-l2 : l2-l1;
  if(l3<ad || l3>l1+l2) return 0.0;
  double P=FTAB[l1+l2-l3]*FTAB[l1-l2+l3]*FTAB[-l1+l2+l3]/FTAB[l1+l2+l3+1]
          *FTAB[l1+m1]*FTAB[l1-m1]*FTAB[l2+m2]*FTAB[l2-m2]*FTAB[l3+m3]*FTAB[l3-m3];
  double spre=csqrt_(P);
  int kmin=0; if(l2-l3-m1>kmin)kmin=l2-l3-m1; if(l1-l3+m2>kmin)kmin=l1-l3+m2;
  int kmax=l1+l2-l3; if(l1-m1<kmax)kmax=l1-m1; if(l2+m2<kmax)kmax=l2+m2;
  double s=0.0;
  for(int k=kmin;k<=kmax;k++){
    double den=FTAB[k]*FTAB[l1+l2-l3-k]*FTAB[l1-m1-k]*FTAB[l2+m2-k]
              *FTAB[l3-l2+m1+k]*FTAB[l3-l1-m2+k];
    s+=((k&1)?-1.0:1.0)/den;
  }
  return csqrt_((double)(2*l3+1))*spre*s;
}

constexpr int lof_(int idx){ int l=0; while((l+1)*(l+1)<=idx) l++; return l; }

struct U2 { int c[2]; double re[2], im[2]; int n; };
constexpr U2 urow_(int idx){
  int l=lof_(idx);
  const double is2=0.70710678118654752440;
  U2 u{}; int off=l*l+l, m=idx-off;
  if(m==0){ u.c[0]=off; u.re[0]=1.0; u.im[0]=0.0; u.n=1; return u; }
  if(m>0){
    double sgn=(m&1)?-1.0:1.0;
    u.c[0]=off+m; u.re[0]=sgn*is2; u.im[0]=0.0;
    u.c[1]=off-m; u.re[1]=is2;     u.im[1]=0.0;
    u.n=2; return u;
  }
  int mm=-m; double sgn=(mm&1)?-1.0:1.0;
  u.c[0]=off-mm; u.re[0]=0.0; u.im[0]=is2;
  u.c[1]=off+mm; u.re[1]=0.0; u.im[1]=-sgn*is2;
  u.n=2; return u;
}

constexpr double realCG_(int i,int j,int k){
  int li=lof_(i), lj=lof_(j), lk=lof_(k);
  U2 ua=urow_(i), ub=urow_(j), uc=urow_(k);
  double Tre=0.0,Tim=0.0;
  for(int a=0;a<ua.n;a++)for(int b=0;b<ub.n;b++)for(int c=0;c<uc.n;c++){
    int ma=ua.c[a]-li*li-li, mb=ub.c[b]-lj*lj-lj, mc=uc.c[c]-lk*lk-lk;
    double cg=cgc_(li,ma,lj,mb,lk,mc);
    if(cg==0.0) continue;
    double xre=ua.re[a]*ub.re[b]-ua.im[a]*ub.im[b];
    double xim=ua.re[a]*ub.im[b]+ua.im[a]*ub.re[b];
    double wre=xre*uc.re[c]+xim*uc.im[c];
    double wim=xim*uc.re[c]-xre*uc.im[c];
    Tre+=wre*cg; Tim+=wim*cg;
  }
  double C=Tre+Tim;
  if(C<1e-12 && C>-1e-12) C=0.0;
  return C;
}

constexpr int path_l(int pi,int which){
  int idx=0;
  for(int l1=0;l1<=4;l1++)for(int l2=0;l2<=4;l2++){
    int lo = l1>l2 ? l1-l2 : l2-l1;
    int hi = (l1+l2<4)?(l1+l2):4;
    for(int l3=lo;l3<=hi;l3++){
      if(idx==pi) return which==0?l1:(which==1?l2:l3);
      idx++;
    }
  }
  return 0;
}

struct EntryList { int n; signed char ia[81]; signed char ib[81]; float v[81]; };

template<int L1,int L2,int L3,int C>
constexpr EntryList build_slot(){
  EntryList E{};
  for(int a=0;a<2*L1+1;a++)for(int b=0;b<2*L2+1;b++){
    double val=realCG_(L1*L1+a, L2*L2+b, L3*L3+C);
    if(val!=0.0){ E.ia[E.n]=(signed char)a; E.ib[E.n]=(signed char)b; E.v[E.n]=(float)val; E.n++; }
  }
  return E;
}

// one small constexpr evaluation per slot (keeps under -fconstexpr-steps; proven to compile)
template<int PI,int C>
constexpr EntryList mk_slot(){
  if constexpr (C < 2*path_l(PI,2)+1)
    return build_slot<path_l(PI,0),path_l(PI,1),path_l(PI,2),C>();
  else
    return EntryList{};
}
template<int PI,int C> struct S2 { static constexpr EntryList E = mk_slot<PI,C>(); };

template<int PI> struct Row9 {
  static constexpr EntryList E[9] = { S2<PI,0>::E, S2<PI,1>::E, S2<PI,2>::E,
                                      S2<PI,3>::E, S2<PI,4>::E, S2<PI,5>::E,
                                      S2<PI,6>::E, S2<PI,7>::E, S2<PI,8>::E };
};

template<int...I> struct iseq{};
template<int N,int...I> struct mkseq : mkseq<N-1,N-1,I...>{};
template<int...I> struct mkseq<0,I...>{ using type=iseq<I...>; };

struct RowPtrs65 { const EntryList* p[65]; };
template<int...PIs> constexpr RowPtrs65 mk_rowptrs(iseq<PIs...>){
  return RowPtrs65{ { Row9<PIs>::E ... } };
}
constexpr RowPtrs65 ROWP = mk_rowptrs(typename mkseq<65>::type{});

// ---- flattened stream: entries grouped by wave (pi%4), then path, then out-channel c ----
#define MAXENT 6000
struct Flat {
  int pb[5];            // path ranges per wave into pmeta
  int eb[5];            // entry begin per wave
  int ne;
  unsigned pmeta[65];   // pi(7b) | entry_count<<7
  unsigned emeta[MAXENT]; // aoff(5b) | boff<<5 | X<<10 | s<<15 | flush<<16
  float    ev[MAXENT];
};

constexpr Flat build_flat(){
  Flat F{};
  int pc=0, ec=0;
  for(int wv=0;wv<4;wv++){
    F.pb[wv]=pc; F.eb[wv]=ec;
    for(int pi=0;pi<65;pi++){
      if(pi%4!=wv) continue;
      int l1=path_l(pi,0), l2=path_l(pi,1), l3=path_l(pi,2);
      int s=(l1+l2+l3)&1;
      int e0=ec;
      for(int c=0;c<2*l3+1;c++){
        const EntryList& EL = ROWP.p[pi][c];
        for(int j=0;j<EL.n;j++){
          F.emeta[ec]=(unsigned)((l1*l1+(int)EL.ia[j]) | ((l2*l2+(int)EL.ib[j])<<5)
                     | ((l3*l3+c)<<10) | (s<<15));
          F.ev[ec]=EL.v[j];
          ec++;
        }
        if(EL.n>0) F.emeta[ec-1] |= (1u<<16);
      }
      F.pmeta[pc]=(unsigned)(pi | ((ec-e0)<<7));
      pc++;
    }
  }
  F.pb[4]=pc; F.eb[4]=ec; F.ne=ec;
  return F;
}
static constexpr Flat FT = build_flat();
static_assert(FT.ne>500 && FT.ne<=MAXENT, "entry table size");

// ======================= init =======================

__global__ __launch_bounds__(256) void k_zero(int* cnt, int N){
  int t=blockIdx.x*256+threadIdx.x; if(t<N) cnt[t]=0;
}

// ======================= edge stage =======================

__global__ __launch_bounds__(256) void k_edge(const int* __restrict__ Z, const int* __restrict__ nbr,
    const float* __restrict__ disp, const float* __restrict__ Wsp,
    float* __restrict__ g, float* __restrict__ Ye, int* cnt, int E){
  int e=blockIdx.x*256+threadIdx.x; if(e>=E) return;
  int i0=nbr[2*e], j0=nbr[2*e+1];
  atomicAdd(&cnt[i0],1);
  int z=Z[j0];
  float dx=disp[3*e], dy=disp[3*e+1], dz=disp[3*e+2];
  float r=sqrtf(dx*dx+dy*dy+dz*dz+1e-12f);
  float inv=1.0f/r;
  float x=dx*inv, y=dy*inv, zz=dz*inv;
  float rc=fminf(r*0.2f,1.0f);
  float fc=0.5f*(cosf(3.14159265358979323846f*rc)+1.0f);
  float rbf[16];
  #pragma unroll
  for(int k=0;k<16;k++){
    float d=r-(float)k*(5.0f/15.0f);
    rbf[k]=expf(-10.24f*d*d)*fc;
  }
  const float* Wz=Wsp + z*256;
  #pragma unroll
  for(int rr=0;rr<16;rr++){
    float s=0.f;
    #pragma unroll
    for(int k=0;k<16;k++) s += rbf[k]*Wz[k*16+rr];
    g[e*16+rr]=s;
  }
  float x2=x*x,y2=y*y,z2=zz*zz;
  float* Y=Ye+(size_t)e*25;
  Y[0]=0.28209479177387814f;
  Y[1]=0.4886025119029199f*y;
  Y[2]=0.4886025119029199f*zz;
  Y[3]=0.4886025119029199f*x;
  Y[4]=1.0925484305920792f*x*y;
  Y[5]=1.0925484305920792f*y*zz;
  Y[6]=0.31539156525252005f*(3.f*z2-1.f);
  Y[7]=1.0925484305920792f*x*zz;
  Y[8]=0.5462742152960396f*(x2-y2);
  Y[9]=0.5900435899266435f*y*(3.f*x2-y2);
  Y[10]=2.890611442640554f*x*y*zz;
  Y[11]=0.4570457994644658f*y*(5.f*z2-1.f);
  Y[12]=0.3731763325901154f*zz*(5.f*z2-3.f);
  Y[13]=0.4570457994644658f*x*(5.f*z2-1.f);
  Y[14]=1.445305721320277f*zz*(x2-y2);
  Y[15]=0.5900435899266435f*x*(x2-3.f*y2);
  Y[16]=2.5033429417967046f*x*y*(x2-y2);
  Y[17]=1.7701307697799304f*y*zz*(3.f*x2-y2);
  Y[18]=0.9461746957575601f*x*y*(7.f*z2-1.f);
  Y[19]=0.6690465435572892f*y*zz*(7.f*z2-3.f);
  Y[20]=0.10578554691520431f*(35.f*z2*z2-30.f*z2+3.f);
  Y[21]=0.6690465435572892f*x*zz*(7.f*z2-3.f);
  Y[22]=0.47308734787878004f*(x2-y2)*(7.f*z2-1.f);
  Y[23]=1.7701307697799304f*x*zz*(x2-3.f*y2);
  Y[24]=0.6258357354491761f*(x2*x2-6.f*x2*y2+y2*y2);
}

// ======================= CSR build =======================

__global__ __launch_bounds__(1024) void k_scan(const int* __restrict__ cnt, int* offs, int* cursor, int N){
  __shared__ int part[1024];
  int t=threadIdx.x;
  int per=(N+1023)>>10;
  int start=t*per;
  int s=0;
  for(int i2=0;i2<per;i2++){int idx=start+i2; if(idx<N) s+=cnt[idx];}
  part[t]=s; __syncthreads();
  for(int off=1;off<1024;off<<=1){
    int v=(t>=off)?part[t-off]:0;
    __syncthreads();
    part[t]+=v;
    __syncthreads();
  }
  int run=(t>0)?part[t-1]:0;
  for(int i2=0;i2<per;i2++){int idx=start+i2; if(idx<N){offs[idx]=run; cursor[idx]=run; run+=cnt[idx];}}
  if(t==1023) offs[N]=part[1023];
}

__global__ __launch_bounds__(256) void k_fill(const int* __restrict__ nbr, int* cursor, int* elist, int E){
  int e=blockIdx.x*256+threadIdx.x; if(e>=E)return;
  int pos=atomicAdd(&cursor[nbr[2*e]],1);
  elist[pos]=e;
}

// ======================= aggregation: y0 -> d_out ch 0..15 =======================

__global__ __launch_bounds__(64) void k_agg(const float* __restrict__ g, const float* __restrict__ Ye,
    const int* __restrict__ offs, const int* __restrict__ elist, const float* __restrict__ norm,
    float* __restrict__ y){
  int n=blockIdx.x, t=threadIdx.x;
  __shared__ float gs[16];
  __shared__ float ys[25];
  float acc[7];
  #pragma unroll
  for(int i2=0;i2<7;i2++) acc[i2]=0.f;
  int e0=offs[n], e1=offs[n+1];
  for(int ei=e0; ei<e1; ei++){
    int e=elist[ei];
    if(t<16) gs[t]=g[(size_t)e*16+t];
    else if(t<41) ys[t-16]=Ye[(size_t)e*25+t-16];
    __syncthreads();
    #pragma unroll
    for(int i2=0;i2<7;i2++){
      int o=t+64*i2;
      if(o<400) acc[i2] += ys[o>>4]*gs[o&15];
    }
    __syncthreads();
  }
  float nv=1.0f/norm[0];
  float* yo=y+(size_t)n*7200;
  #pragma unroll
  for(int i2=0;i2<7;i2++){
    int o=t+64*i2;
    if(o<400){ int lm=o>>4,k=o&15; yo[lm*144+k]=acc[i2]*nv; yo[3600+lm*144+k]=0.f; }
  }
}

// ======================= TP layer 0 — 4 waves/atom, streamed CG table =======================

__global__ __launch_bounds__(256,6) void k_tp0(float* __restrict__ y, const float* __restrict__ W1,
    const float* __restrict__ W2, const float* __restrict__ wp, const Flat* __restrict__ ft){
  int n=blockIdx.x, tid=threadIdx.x, f=tid&63, wv=tid>>6;
  __shared__ __align__(16) float y0s[400];
  __shared__ __align__(16) float aS[1600];
  __shared__ __align__(16) float bS[1600];
  __shared__ __align__(16) float outS[3200];
  const float* yin = y + (size_t)n*7200;
  for(int t=tid;t<400;t+=256) y0s[t]=yin[(t>>4)*144+(t&15)];
  for(int t=tid;t<3200;t+=256) outS[t]=0.f;
  __syncthreads();
  const int asg0[5]={3,3,2,1,0};
  #pragma unroll
  for(int l=0;l<5;l++){
    if(asg0[l]!=wv) continue;
    const int n1=2*l+1, base=l*l;
    float accA[9],accB[9];
    #pragma unroll
    for(int j2=0;j2<9;j2++){accA[j2]=0.f;accB[j2]=0.f;}
    const float* w1=W1+l*1024+f;
    const float* w2=W2+l*1024+f;
    #pragma unroll
    for(int k=0;k<16;k+=4){
      float u1_0=w1[k*64],u1_1=w1[(k+1)*64],u1_2=w1[(k+2)*64],u1_3=w1[(k+3)*64];
      float u2_0=w2[k*64],u2_1=w2[(k+1)*64],u2_2=w2[(k+2)*64],u2_3=w2[(k+3)*64];
      #pragma unroll
      for(int j2=0;j2<n1;j2++){
        const float4 yv=*reinterpret_cast<const float4*>(&y0s[(base+j2)*16+k]);
        accA[j2]+=yv.x*u1_0+yv.y*u1_1+yv.z*u1_2+yv.w*u1_3;
        accB[j2]+=yv.x*u2_0+yv.y*u2_1+yv.z*u2_2+yv.w*u2_3;
      }
    }
    #pragma unroll
    for(int j2=0;j2<n1;j2++){ aS[(base+j2)*64+f]=accA[j2]; bS[(base+j2)*64+f]=accB[j2]; }
  }
  __syncthreads();
  {
    const unsigned* __restrict__ EM=ft->emeta;
    const float* __restrict__ EV=ft->ev;
    int pp0=ft->pb[wv], pp1=ft->pb[wv+1];
    int e=ft->eb[wv];
    for(int pp=pp0;pp<pp1;pp++){
      unsigned pm=ft->pmeta[pp];
      int pi=(int)(pm&127u), ec=(int)(pm>>7);
      float w00=wp[pi*256+f];
      float r=0.f;
      #pragma unroll 4
      for(int t=0;t<ec;t++,e++){
        unsigned m=EM[e]; float v=EV[e];
        r += v*aS[(m&31u)*64+f]*bS[((m>>5)&31u)*64+f];
        if(m&65536u){
          int X=(int)((m>>10)&31u), s=(int)((m>>15)&1u);
          atomicAdd(&outS[(s*25+X)*64+f], w00*r);
          r=0.f;
        }
      }
    }
  }
  __syncthreads();
  float* yo=y+(size_t)n*7200+16;
  for(int t2=wv;t2<50;t2+=4) yo[t2*144+f]=outS[t2*64+f];
}

// ======================= TP layer 1 — 4 waves/atom, streamed CG table =======================

__global__ __launch_bounds__(256,4) void k_tp1(float* __restrict__ y, const float* __restrict__ W1,
    const float* __restrict__ W2, const float* __restrict__ wp, const Flat* __restrict__ ft){
  int n=blockIdx.x, tid=threadIdx.x, f=tid&63, wv=tid>>6;
  __shared__ __align__(16) float bufA[3200];          // y1s, then outS
  __shared__ __align__(16) float2 aS[1600];           // [lm*64+f] = (parity0, parity1)
  __shared__ __align__(16) float2 bS[1600];
  const float* yin = y + (size_t)n*7200 + 16;
  for(int t=tid;t<3200;t+=256) bufA[t]=yin[(t>>6)*144+(t&63)];
  __syncthreads();
  const int asg[10]={2,0,2,2,0,3,1,3,3,1};
  #pragma unroll
  for(int p=0;p<2;p++){
    #pragma unroll
    for(int l=0;l<5;l++){
      if(asg[p*5+l]!=wv) continue;
      const int n1=2*l+1, base=l*l;
      float accA[9],accB[9];
      #pragma unroll
      for(int j2=0;j2<9;j2++){accA[j2]=0.f;accB[j2]=0.f;}
      const float* w1=W1+(p*5+l)*4096+f;
      const float* w2=W2+(p*5+l)*4096+f;
      #pragma unroll 4
      for(int k=0;k<64;k+=4){
        float u1_0=w1[k*64],u1_1=w1[(k+1)*64],u1_2=w1[(k+2)*64],u1_3=w1[(k+3)*64];
        float u2_0=w2[k*64],u2_1=w2[(k+1)*64],u2_2=w2[(k+2)*64],u2_3=w2[(k+3)*64];
        #pragma unroll
        for(int j2=0;j2<n1;j2++){
          const float4 yv=*reinterpret_cast<const float4*>(&bufA[(p*25+base+j2)*64+k]);
          accA[j2]+=yv.x*u1_0+yv.y*u1_1+yv.z*u1_2+yv.w*u1_3;
          accB[j2]+=yv.x*u2_0+yv.y*u2_1+yv.z*u2_2+yv.w*u2_3;
        }
      }
      #pragma unroll
      for(int j2=0;j2<n1;j2++){
        if(p==0){ aS[(base+j2)*64+f].x=accA[j2]; bS[(base+j2)*64+f].x=accB[j2]; }
        else    { aS[(base+j2)*64+f].y=accA[j2]; bS[(base+j2)*64+f].y=accB[j2]; }
      }
    }
  }
  __syncthreads();
  for(int t=tid;t<3200;t+=256) bufA[t]=0.f;   // bufA becomes outS
  __syncthreads();
  {
    const unsigned* __restrict__ EM=ft->emeta;
    const float* __restrict__ EV=ft->ev;
    int pp0=ft->pb[wv], pp1=ft->pb[wv+1];
    int e=ft->eb[wv];
    for(int pp=pp0;pp<pp1;pp++){
      unsigned pm=ft->pmeta[pp];
      int pi=(int)(pm&127u), ec=(int)(pm>>7);
      const float* wpp=wp+pi*256+f;
      float w00=wpp[0], w01=wpp[64], w10=wpp[128], w11=wpp[192];
      float r00=0.f,r01=0.f,r10=0.f,r11=0.f;
      #pragma unroll 4
      for(int t=0;t<ec;t++,e++){
        unsigned m=EM[e]; float v=EV[e];
        float2 av=aS[(m&31u)*64+f];
        float2 bv=bS[((m>>5)&31u)*64+f];
        float p=v*av.x, q=v*av.y;
        r00+=p*bv.x; r01+=p*bv.y; r10+=q*bv.x; r11+=q*bv.y;
        if(m&65536u){
          int X=(int)((m>>10)&31u), s=(int)((m>>15)&1u);
          atomicAdd(&bufA[(s*25+X)*64+f],     w00*r00+w11*r11);   // even
          atomicAdd(&bufA[((1-s)*25+X)*64+f], w01*r01+w10*r10);   // odd
          r00=0.f;r01=0.f;r10=0.f;r11=0.f;
        }
      }
    }
  }
  __syncthreads();
  float* yo=y+(size_t)n*7200+80;
  for(int t2=wv;t2<50;t2+=4) yo[t2*144+f]=bufA[t2*64+f];
}

// ======================= final =======================

__device__ const int DEGLM[25]={0,1,1,1,2,2,2,2,2,3,3,3,3,3,3,3,4,4,4,4,4,4,4,4,4};

__global__ __launch_bounds__(128) void k_final(float* __restrict__ y, const int* __restrict__ Z,
    const float* __restrict__ emb, const float* __restrict__ Wet, const float* __restrict__ bet,
    const float* __restrict__ wf){
  int n=blockIdx.x, t=threadIdx.x;
  __shared__ float embs[64];
  __shared__ float teS[144];
  int z=Z[n];
  if(t<64) embs[t]=emb[z*64+t];
  __syncthreads();
  for(int c=t;c<144;c+=128){
    float s=bet[c];
    for(int d=0;d<64;d++) s+=embs[d]*Wet[d*144+c];
    teS[c]=s;
  }
  __syncthreads();
  float* yo=y+(size_t)n*7200;
  for(int row=0;row<50;row++){
    int p=row/25, lm=row-25*p;
    const float* wrow=wf+(p*5+DEGLM[lm])*144;
    for(int c=t;c<144;c+=128){
      float v=yo[row*144+c];
      float te=teS[c];
      v=te*v*wrow[c];
      if(row==0) v+=te;
      float sp=log1pf(expf(v));
      v=v+v*tanhf(sp);
      yo[row*144+c]=v;
    }
  }
}

// ======================= launch =======================

extern "C" void kernel_launch(void* const* d_in, const int* in_sizes, int n_in,
                              void* d_out, int out_size, void* d_ws, size_t ws_size,
                              hipStream_t stream) {
  const int*   Z    =(const int*)  d_in[0];
  const int*   nbr  =(const int*)  d_in[1];
  const float* disp =(const float*)d_in[2];
  const float* Wsp  =(const float*)d_in[3];
  const float* emb  =(const float*)d_in[4];
  const float* Wet  =(const float*)d_in[5];
  const float* bet  =(const float*)d_in[6];
  const float* norm =(const float*)d_in[7];
  const float* t0W1 =(const float*)d_in[8];
  const float* t0W2 =(const float*)d_in[9];
  const float* t0wp =(const float*)d_in[10];
  const float* t1W1 =(const float*)d_in[11];
  const float* t1W2 =(const float*)d_in[12];
  const float* t1wp =(const float*)d_in[13];
  const float* wf   =(const float*)d_in[14];
  int N=in_sizes[0];
  int E=in_sizes[1]/2;
  float* y=(float*)d_out;

  char* w=(char*)d_ws;
  size_t off=0;
  auto take=[&](size_t bytes)->void*{ size_t cur=(off+255)&~(size_t)255; off=cur+bytes; return (void*)(w+cur); };
  Flat*  tab   =(Flat*) take(sizeof(Flat));
  int*   cnt   =(int*)  take((size_t)N*4);
  int*   offs  =(int*)  take((size_t)(N+1)*4);
  int*   cursor=(int*)  take((size_t)N*4);
  int*   elist =(int*)  take((size_t)E*4);
  float* g     =(float*)take((size_t)E*16*4);
  float* Ye    =(float*)take((size_t)E*25*4);
  (void)ws_size; (void)out_size; (void)n_in;

  hipMemcpyAsync(tab, &FT, sizeof(Flat), hipMemcpyHostToDevice, stream);

  k_zero   <<<dim3((N+255)/256),   dim3(256), 0, stream>>>(cnt, N);
  k_edge   <<<dim3((E+255)/256),   dim3(256), 0, stream>>>(Z, nbr, disp, Wsp, g, Ye, cnt, E);
  k_scan   <<<dim3(1),             dim3(1024),0, stream>>>(cnt, offs, cursor, N);
  k_fill   <<<dim3((E+255)/256),   dim3(256), 0, stream>>>(nbr, cursor, elist, E);
  k_agg    <<<dim3(N),             dim3(64),  0, stream>>>(g, Ye, offs, elist, norm, y);
  k_tp0    <<<dim3(N),             dim3(256), 0, stream>>>(y, t0W1, t0W2, t0wp, tab);
  k_tp1    <<<dim3(N),             dim3(256), 0, stream>>>(y, t1W1, t1W2, t1wp, tab);
  k_final  <<<dim3(N),             dim3(128), 0, stream>>>(y, Z, emb, Wet, bet, wf);
}

// Round 4
// 1583.878 us; speedup vs baseline: 3.5441x; 3.5441x over previous
//
#include <hip/hip_runtime.h>
#include <math.h>

// ======================= compile-time real Clebsch-Gordan tables =======================

constexpr double FTAB[14]={1.0,1.0,2.0,6.0,24.0,120.0,720.0,5040.0,40320.0,362880.0,
                           3628800.0,39916800.0,479001600.0,6227020800.0};

constexpr double csqrt_(double x){
  if(x<=0.0) return 0.0;
  double g = x<1.0 ? 1.0 : x;
  for(int i=0;i<60;i++){
    double ng=0.5*(g+x/g);
    if(ng==g) break;
    g=ng;
  }
  return g;
}

constexpr double cgc_(int l1,int m1,int l2,int m2,int l3,int m3){
  if(m1+m2!=m3) return 0.0;
  int ad = l1>l2 ? l1-l2 : l2-l1;
  if(l3<ad || l3>l1+l2) return 0.0;
  double P=FTAB[l1+l2-l3]*FTAB[l1-l2+l3]*FTAB[-l1+l2+l3]/FTAB[l1+l2+l3+1]
          *FTAB[l1+m1]*FTAB[l1-m1]*FTAB[l2+m2]*FTAB[l2-m2]*FTAB[l3+m3]*FTAB[l3-m3];
  double spre=csqrt_(P);
  int kmin=0; if(l2-l3-m1>kmin)kmin=l2-l3-m1; if(l1-l3+m2>kmin)kmin=l1-l3+m2;
  int kmax=l1+l2-l3; if(l1-m1<kmax)kmax=l1-m1; if(l2+m2<kmax)kmax=l2+m2;
  double s=0.0;
  for(int k=kmin;k<=kmax;k++){
    double den=FTAB[k]*FTAB[l1+l2-l3-k]*FTAB[l1-m1-k]*FTAB[l2+m2-k]
              *FTAB[l3-l2+m1+k]*FTAB[l3-l1-m2+k];
    s+=((k&1)?-1.0:1.0)/den;
  }
  return csqrt_((double)(2*l3+1))*spre*s;
}

constexpr int lof_(int idx){ int l=0; while((l+1)*(l+1)<=idx) l++; return l; }

struct U2 { int c[2]; double re[2], im[2]; int n; };
constexpr U2 urow_(int idx){
  int l=lof_(idx);
  const double is2=0.70710678118654752440;
  U2 u{}; int off=l*l+l, m=idx-off;
  if(m==0){ u.c[0]=off; u.re[0]=1.0; u.im[0]=0.0; u.n=1; return u; }
  if(m>0){
    double sgn=(m&1)?-1.0:1.0;
    u.c[0]=off+m; u.re[0]=sgn*is2; u.im[0]=0.0;
    u.c[1]=off-m; u.re[1]=is2;     u.im[1]=0.0;
    u.n=2; return u;
  }
  int mm=-m; double sgn=(mm&1)?-1.0:1.0;
  u.c[0]=off-mm; u.re[0]=0.0; u.im[0]=is2;
  u.c[1]=off+mm; u.re[1]=0.0; u.im[1]=-sgn*is2;
  u.n=2; return u;
}

constexpr double realCG_(int i,int j,int k){
  int li=lof_(i), lj=lof_(j), lk=lof_(k);
  U2 ua=urow_(i), ub=urow_(j), uc=urow_(k);
  double Tre=0.0,Tim=0.0;
  for(int a=0;a<ua.n;a++)for(int b=0;b<ub.n;b++)for(int c=0;c<uc.n;c++){
    int ma=ua.c[a]-li*li-li, mb=ub.c[b]-lj*lj-lj, mc=uc.c[c]-lk*lk-lk;
    double cg=cgc_(li,ma,lj,mb,lk,mc);
    if(cg==0.0) continue;
    double xre=ua.re[a]*ub.re[b]-ua.im[a]*ub.im[b];
    double xim=ua.re[a]*ub.im[b]+ua.im[a]*ub.re[b];
    double wre=xre*uc.re[c]+xim*uc.im[c];
    double wim=xim*uc.re[c]-xre*uc.im[c];
    Tre+=wre*cg; Tim+=wim*cg;
  }
  double C=Tre+Tim;
  if(C<1e-12 && C>-1e-12) C=0.0;
  return C;
}

constexpr int path_l(int pi,int which){
  int idx=0;
  for(int l1=0;l1<=4;l1++)for(int l2=0;l2<=4;l2++){
    int lo = l1>l2 ? l1-l2 : l2-l1;
    int hi = (l1+l2<4)?(l1+l2):4;
    for(int l3=lo;l3<=hi;l3++){
      if(idx==pi) return which==0?l1:(which==1?l2:l3);
      idx++;
    }
  }
  return 0;
}

struct EntryList { int n; signed char ia[81]; signed char ib[81]; float v[81]; };

template<int L1,int L2,int L3,int C>
constexpr EntryList build_slot(){
  EntryList E{};
  for(int a=0;a<2*L1+1;a++)for(int b=0;b<2*L2+1;b++){
    double val=realCG_(L1*L1+a, L2*L2+b, L3*L3+C);
    if(val!=0.0){ E.ia[E.n]=(signed char)a; E.ib[E.n]=(signed char)b; E.v[E.n]=(float)val; E.n++; }
  }
  return E;
}
template<int L1,int L2,int L3,int C>
struct SlotTab { static constexpr EntryList E = build_slot<L1,L2,L3,C>(); };

template<int...I> struct iseq{};
template<int N,int...I> struct mkseq : mkseq<N-1,N-1,I...>{};
template<int...I> struct mkseq<0,I...>{ using type=iseq<I...>; };

// lane broadcast via v_readlane (uniform result, no LDS)
__device__ __forceinline__ float rl(float v,int k){
  return __int_as_float(__builtin_amdgcn_readlane(__float_as_int(v),k));
}

// ======================= register CG contraction, l3-major (tp0: single parity) ===========

template<int L3,int PI,int C>
__device__ __forceinline__ void t0_slot(const float(&a)[25],const float(&b)[25],
                                        float(&o0)[9],float(&o1)[9],float w00){
  constexpr int L1=path_l(PI,0),L2=path_l(PI,1);
  using ST=SlotTab<L1,L2,L3,C>;
  if constexpr(ST::E.n>0){
    float r=0.f;
    #pragma unroll
    for(int j=0;j<ST::E.n;j++)
      r += ST::E.v[j]*a[L1*L1+(int)ST::E.ia[j]]*b[L2*L2+(int)ST::E.ib[j]];
    constexpr int Sp=(L1+L2+L3)&1;
    if constexpr(Sp==0) o0[C]+=w00*r; else o1[C]+=w00*r;
  }
}
template<int L3,int PI,int...Cs>
__device__ __forceinline__ void t0_cs(iseq<Cs...>,const float(&a)[25],const float(&b)[25],
                                      float(&o0)[9],float(&o1)[9],float w00){
  (t0_slot<L3,PI,Cs>(a,b,o0,o1,w00), ...);
}
template<int L3,int PI>
__device__ __forceinline__ void t0_path(const float(&a)[25],const float(&b)[25],
                                        float(&o0)[9],float(&o1)[9],const float* __restrict__ wp,int f){
  if constexpr(path_l(PI,2)==L3){
    float w00=wp[PI*256+f];
    t0_cs<L3,PI>(typename mkseq<2*L3+1>::type{}, a,b,o0,o1,w00);
  }
}
template<int L3,int...PIs>
__device__ __forceinline__ void t0_l3(iseq<PIs...>,const float(&a)[25],const float(&b)[25],
                                      const float* __restrict__ wp,int f,float* __restrict__ yo){
  float o0[9],o1[9];
  #pragma unroll
  for(int c=0;c<9;c++){o0[c]=0.f;o1[c]=0.f;}
  (t0_path<L3,PIs>(a,b,o0,o1,wp,f), ...);
  #pragma unroll
  for(int c=0;c<2*L3+1;c++){
    yo[(L3*L3+c)*144+f]      = o0[c];
    yo[3600+(L3*L3+c)*144+f] = o1[c];
  }
}

// ======================= register CG contraction, l3-major (tp1: two parities) ============

template<int L3,int PI,int C>
__device__ __forceinline__ void t1_slot(const float(&a0)[25],const float(&a1)[25],
                                        const float(&b0)[25],const float(&b1)[25],
                                        float(&o0)[9],float(&o1)[9],
                                        float w00,float w01,float w10,float w11){
  constexpr int L1=path_l(PI,0),L2=path_l(PI,1);
  using ST=SlotTab<L1,L2,L3,C>;
  if constexpr(ST::E.n>0){
    float r00=0.f,r01=0.f,r10=0.f,r11=0.f;
    #pragma unroll
    for(int j=0;j<ST::E.n;j++){
      constexpr_helper: ;
      float v=ST::E.v[j];
      float av0=a0[L1*L1+(int)ST::E.ia[j]], av1=a1[L1*L1+(int)ST::E.ia[j]];
      float bv0=b0[L2*L2+(int)ST::E.ib[j]], bv1=b1[L2*L2+(int)ST::E.ib[j]];
      float p=v*av0, q=v*av1;
      r00+=p*bv0; r01+=p*bv1; r10+=q*bv0; r11+=q*bv1;
    }
    constexpr int Sp=(L1+L2+L3)&1;
    float ev=w00*r00+w11*r11, od=w01*r01+w10*r10;
    if constexpr(Sp==0){ o0[C]+=ev; o1[C]+=od; }
    else               { o1[C]+=ev; o0[C]+=od; }
  }
}
template<int L3,int PI,int...Cs>
__device__ __forceinline__ void t1_cs(iseq<Cs...>,const float(&a0)[25],const float(&a1)[25],
                                      const float(&b0)[25],const float(&b1)[25],
                                      float(&o0)[9],float(&o1)[9],
                                      float w00,float w01,float w10,float w11){
  (t1_slot<L3,PI,Cs>(a0,a1,b0,b1,o0,o1,w00,w01,w10,w11), ...);
}
template<int L3,int PI>
__device__ __forceinline__ void t1_path(const float(&a0)[25],const float(&a1)[25],
                                        const float(&b0)[25],const float(&b1)[25],
                                        float(&o0)[9],float(&o1)[9],const float* __restrict__ wp,int f){
  if constexpr(path_l(PI,2)==L3){
    const float* wpp=wp+PI*256+f;
    float w00=wpp[0], w01=wpp[64], w10=wpp[128], w11=wpp[192];
    t1_cs<L3,PI>(typename mkseq<2*L3+1>::type{}, a0,a1,b0,b1,o0,o1,w00,w01,w10,w11);
  }
}
template<int L3,int...PIs>
__device__ __forceinline__ void t1_l3(iseq<PIs...>,const float(&a0)[25],const float(&a1)[25],
                                      const float(&b0)[25],const float(&b1)[25],
                                      const float* __restrict__ wp,int f,float* __restrict__ yo){
  float o0[9],o1[9];
  #pragma unroll
  for(int c=0;c<9;c++){o0[c]=0.f;o1[c]=0.f;}
  (t1_path<L3,PIs>(a0,a1,b0,b1,o0,o1,wp,f), ...);
  #pragma unroll
  for(int c=0;c<2*L3+1;c++){
    yo[(L3*L3+c)*144+f]      = o0[c];
    yo[3600+(L3*L3+c)*144+f] = o1[c];
  }
}

// ======================= init =======================

__global__ __launch_bounds__(256) void k_zero(int* cnt, int N){
  int t=blockIdx.x*256+threadIdx.x; if(t<N) cnt[t]=0;
}

// ======================= edge stage =======================

__global__ __launch_bounds__(256) void k_edge(const int* __restrict__ Z, const int* __restrict__ nbr,
    const float* __restrict__ disp, const float* __restrict__ Wsp,
    float* __restrict__ g, float* __restrict__ Ye, int* cnt, int E){
  int e=blockIdx.x*256+threadIdx.x; if(e>=E) return;
  int i0=nbr[2*e], j0=nbr[2*e+1];
  atomicAdd(&cnt[i0],1);
  int z=Z[j0];
  float dx=disp[3*e], dy=disp[3*e+1], dz=disp[3*e+2];
  float r=sqrtf(dx*dx+dy*dy+dz*dz+1e-12f);
  float inv=1.0f/r;
  float x=dx*inv, y=dy*inv, zz=dz*inv;
  float rc=fminf(r*0.2f,1.0f);
  float fc=0.5f*(cosf(3.14159265358979323846f*rc)+1.0f);
  float rbf[16];
  #pragma unroll
  for(int k=0;k<16;k++){
    float d=r-(float)k*(5.0f/15.0f);
    rbf[k]=expf(-10.24f*d*d)*fc;
  }
  const float* Wz=Wsp + z*256;
  #pragma unroll
  for(int rr=0;rr<16;rr++){
    float s=0.f;
    #pragma unroll
    for(int k=0;k<16;k++) s += rbf[k]*Wz[k*16+rr];
    g[e*16+rr]=s;
  }
  float x2=x*x,y2=y*y,z2=zz*zz;
  float* Y=Ye+(size_t)e*25;
  Y[0]=0.28209479177387814f;
  Y[1]=0.4886025119029199f*y;
  Y[2]=0.4886025119029199f*zz;
  Y[3]=0.4886025119029199f*x;
  Y[4]=1.0925484305920792f*x*y;
  Y[5]=1.0925484305920792f*y*zz;
  Y[6]=0.31539156525252005f*(3.f*z2-1.f);
  Y[7]=1.0925484305920792f*x*zz;
  Y[8]=0.5462742152960396f*(x2-y2);
  Y[9]=0.5900435899266435f*y*(3.f*x2-y2);
  Y[10]=2.890611442640554f*x*y*zz;
  Y[11]=0.4570457994644658f*y*(5.f*z2-1.f);
  Y[12]=0.3731763325901154f*zz*(5.f*z2-3.f);
  Y[13]=0.4570457994644658f*x*(5.f*z2-1.f);
  Y[14]=1.445305721320277f*zz*(x2-y2);
  Y[15]=0.5900435899266435f*x*(x2-3.f*y2);
  Y[16]=2.5033429417967046f*x*y*(x2-y2);
  Y[17]=1.7701307697799304f*y*zz*(3.f*x2-y2);
  Y[18]=0.9461746957575601f*x*y*(7.f*z2-1.f);
  Y[19]=0.6690465435572892f*y*zz*(7.f*z2-3.f);
  Y[20]=0.10578554691520431f*(35.f*z2*z2-30.f*z2+3.f);
  Y[21]=0.6690465435572892f*x*zz*(7.f*z2-3.f);
  Y[22]=0.47308734787878004f*(x2-y2)*(7.f*z2-1.f);
  Y[23]=1.7701307697799304f*x*zz*(x2-3.f*y2);
  Y[24]=0.6258357354491761f*(x2*x2-6.f*x2*y2+y2*y2);
}

// ======================= CSR build =======================

__global__ __launch_bounds__(1024) void k_scan(const int* __restrict__ cnt, int* offs, int* cursor, int N){
  __shared__ int part[1024];
  int t=threadIdx.x;
  int per=(N+1023)>>10;
  int start=t*per;
  int s=0;
  for(int i2=0;i2<per;i2++){int idx=start+i2; if(idx<N) s+=cnt[idx];}
  part[t]=s; __syncthreads();
  for(int off=1;off<1024;off<<=1){
    int v=(t>=off)?part[t-off]:0;
    __syncthreads();
    part[t]+=v;
    __syncthreads();
  }
  int run=(t>0)?part[t-1]:0;
  for(int i2=0;i2<per;i2++){int idx=start+i2; if(idx<N){offs[idx]=run; cursor[idx]=run; run+=cnt[idx];}}
  if(t==1023) offs[N]=part[1023];
}

__global__ __launch_bounds__(256) void k_fill(const int* __restrict__ nbr, int* cursor, int* elist, int E){
  int e=blockIdx.x*256+threadIdx.x; if(e>=E)return;
  int pos=atomicAdd(&cursor[nbr[2*e]],1);
  elist[pos]=e;
}

// ======================= aggregation: y0 -> d_out ch 0..15 =======================

__global__ __launch_bounds__(64) void k_agg(const float* __restrict__ g, const float* __restrict__ Ye,
    const int* __restrict__ offs, const int* __restrict__ elist, const float* __restrict__ norm,
    float* __restrict__ y){
  int n=blockIdx.x, t=threadIdx.x;
  __shared__ float gs[16];
  __shared__ float ys[25];
  float acc[7];
  #pragma unroll
  for(int i2=0;i2<7;i2++) acc[i2]=0.f;
  int e0=offs[n], e1=offs[n+1];
  for(int ei=e0; ei<e1; ei++){
    int e=elist[ei];
    if(t<16) gs[t]=g[(size_t)e*16+t];
    else if(t<41) ys[t-16]=Ye[(size_t)e*25+t-16];
    __syncthreads();
    #pragma unroll
    for(int i2=0;i2<7;i2++){
      int o=t+64*i2;
      if(o<400) acc[i2] += ys[o>>4]*gs[o&15];
    }
    __syncthreads();
  }
  float nv=1.0f/norm[0];
  float* yo=y+(size_t)n*7200;
  #pragma unroll
  for(int i2=0;i2<7;i2++){
    int o=t+64*i2;
    if(o<400){ int lm=o>>4,k=o&15; yo[lm*144+k]=acc[i2]*nv; yo[3600+lm*144+k]=0.f; }
  }
}

// ======================= TP layer 0 — 1 wave/atom, all-register =======================

__global__ __launch_bounds__(64,4) void k_tp0(float* __restrict__ y, const float* __restrict__ W1,
    const float* __restrict__ W2, const float* __restrict__ wp){
  int n=blockIdx.x, f=threadIdx.x;
  float* ybase = y + (size_t)n*7200;
  float a[25],b[25];
  #pragma unroll
  for(int i=0;i<25;i++){a[i]=0.f;b[i]=0.f;}
  #pragma unroll
  for(int l=0;l<5;l++){
    const int n1=2*l+1, base=l*l;
    float yk[9];
    #pragma unroll
    for(int j=0;j<n1;j++) yk[j]=ybase[(base+j)*144+f];   // lane = k (only k<16 consumed)
    const float* w1=W1+l*1024+f;
    const float* w2=W2+l*1024+f;
    #pragma unroll 8
    for(int k=0;k<16;k++){
      float u1=w1[k*64], u2=w2[k*64];
      #pragma unroll
      for(int j=0;j<n1;j++){
        float yv=rl(yk[j],k);
        a[base+j]+=yv*u1; b[base+j]+=yv*u2;
      }
    }
  }
  float* yo=ybase+16;
  t0_l3<0>(typename mkseq<65>::type{}, a,b,wp,f,yo);
  t0_l3<1>(typename mkseq<65>::type{}, a,b,wp,f,yo);
  t0_l3<2>(typename mkseq<65>::type{}, a,b,wp,f,yo);
  t0_l3<3>(typename mkseq<65>::type{}, a,b,wp,f,yo);
  t0_l3<4>(typename mkseq<65>::type{}, a,b,wp,f,yo);
}

// ======================= TP layer 1 — 1 wave/atom, all-register =======================

__global__ __launch_bounds__(64,3) void k_tp1(float* __restrict__ y, const float* __restrict__ W1,
    const float* __restrict__ W2, const float* __restrict__ wp){
  int n=blockIdx.x, f=threadIdx.x;
  float* ybase = y + (size_t)n*7200;
  const float* yin = ybase + 16;
  float a0[25],a1[25],b0[25],b1[25];
  #pragma unroll
  for(int i=0;i<25;i++){a0[i]=0.f;a1[i]=0.f;b0[i]=0.f;b1[i]=0.f;}
  #pragma unroll
  for(int p=0;p<2;p++){
    #pragma unroll
    for(int l=0;l<5;l++){
      const int n1=2*l+1, base=l*l;
      float yk[9];
      #pragma unroll
      for(int j=0;j<n1;j++) yk[j]=yin[p*3600+(base+j)*144+f];   // lane = k
      const float* w1=W1+(p*5+l)*4096+f;
      const float* w2=W2+(p*5+l)*4096+f;
      #pragma unroll 8
      for(int k=0;k<64;k++){
        float u1=w1[k*64], u2=w2[k*64];
        #pragma unroll
        for(int j=0;j<n1;j++){
          float yv=rl(yk[j],k);
          if(p==0){ a0[base+j]+=yv*u1; b0[base+j]+=yv*u2; }
          else    { a1[base+j]+=yv*u1; b1[base+j]+=yv*u2; }
        }
      }
    }
  }
  float* yo=ybase+80;
  t1_l3<0>(typename mkseq<65>::type{}, a0,a1,b0,b1,wp,f,yo);
  t1_l3<1>(typename mkseq<65>::type{}, a0,a1,b0,b1,wp,f,yo);
  t1_l3<2>(typename mkseq<65>::type{}, a0,a1,b0,b1,wp,f,yo);
  t1_l3<3>(typename mkseq<65>::type{}, a0,a1,b0,b1,wp,f,yo);
  t1_l3<4>(typename mkseq<65>::type{}, a0,a1,b0,b1,wp,f,yo);
}

// ======================= final =======================

__device__ const int DEGLM[25]={0,1,1,1,2,2,2,2,2,3,3,3,3,3,3,3,4,4,4,4,4,4,4,4,4};

__global__ __launch_bounds__(128) void k_final(float* __restrict__ y, const int* __restrict__ Z,
    const float* __restrict__ emb, const float* __restrict__ Wet, const float* __restrict__ bet,
    const float* __restrict__ wf){
  int n=blockIdx.x, t=threadIdx.x;
  __shared__ float embs[64];
  __shared__ float teS[144];
  int z=Z[n];
  if(t<64) embs[t]=emb[z*64+t];
  __syncthreads();
  for(int c=t;c<144;c+=128){
    float s=bet[c];
    for(int d=0;d<64;d++) s+=embs[d]*Wet[d*144+c];
    teS[c]=s;
  }
  __syncthreads();
  float* yo=y+(size_t)n*7200;
  for(int row=0;row<50;row++){
    int p=row/25, lm=row-25*p;
    const float* wrow=wf+(p*5+DEGLM[lm])*144;
    for(int c=t;c<144;c+=128){
      float v=yo[row*144+c];
      float te=teS[c];
      v=te*v*wrow[c];
      if(row==0) v+=te;
      float sp=log1pf(expf(v));
      v=v+v*tanhf(sp);
      yo[row*144+c]=v;
    }
  }
}

// ======================= launch =======================

extern "C" void kernel_launch(void* const* d_in, const int* in_sizes, int n_in,
                              void* d_out, int out_size, void* d_ws, size_t ws_size,
                              hipStream_t stream) {
  const int*   Z    =(const int*)  d_in[0];
  const int*   nbr  =(const int*)  d_in[1];
  const float* disp =(const float*)d_in[2];
  const float* Wsp  =(const float*)d_in[3];
  const float* emb  =(const float*)d_in[4];
  const float* Wet  =(const float*)d_in[5];
  const float* bet  =(const float*)d_in[6];
  const float* norm =(const float*)d_in[7];
  const float* t0W1 =(const float*)d_in[8];
  const float* t0W2 =(const float*)d_in[9];
  const float* t0wp =(const float*)d_in[10];
  const float* t1W1 =(const float*)d_in[11];
  const float* t1W2 =(const float*)d_in[12];
  const float* t1wp =(const float*)d_in[13];
  const float* wf   =(const float*)d_in[14];
  int N=in_sizes[0];
  int E=in_sizes[1]/2;
  float* y=(float*)d_out;

  char* w=(char*)d_ws;
  size_t off=0;
  auto take=[&](size_t bytes)->void*{ size_t cur=(off+255)&~(size_t)255; off=cur+bytes; return (void*)(w+cur); };
  int*   cnt   =(int*)  take((size_t)N*4);
  int*   offs  =(int*)  take((size_t)(N+1)*4);
  int*   cursor=(int*)  take((size_t)N*4);
  int*   elist =(int*)  take((size_t)E*4);
  float* g     =(float*)take((size_t)E*16*4);
  float* Ye    =(float*)take((size_t)E*25*4);
  (void)ws_size; (void)out_size; (void)n_in;

  k_zero   <<<dim3((N+255)/256),   dim3(256), 0, stream>>>(cnt, N);
  k_edge   <<<dim3((E+255)/256),   dim3(256), 0, stream>>>(Z, nbr, disp, Wsp, g, Ye, cnt, E);
  k_scan   <<<dim3(1),             dim3(1024),0, stream>>>(cnt, offs, cursor, N);
  k_fill   <<<dim3((E+255)/256),   dim3(256), 0, stream>>>(nbr, cursor, elist, E);
  k_agg    <<<dim3(N),             dim3(64),  0, stream>>>(g, Ye, offs, elist, norm, y);
  k_tp0    <<<dim3(N),             dim3(64),  0, stream>>>(y, t0W1, t0W2, t0wp);
  k_tp1    <<<dim3(N),             dim3(64),  0, stream>>>(y, t1W1, t1W2, t1wp);
  k_final  <<<dim3(N),             dim3(128), 0, stream>>>(y, Z, emb, Wet, bet, wf);
}